// Round 1
// baseline (235.642 us; speedup 1.0000x reference)
//
#include <hip/hip_runtime.h>
#include <math.h>

#define B_ 4
#define N_ 512
#define D_ 64
#define NDIAG (2 * N_ - 1)  // 1023

// Phase 1: D[b][i][j] = ||x[b,i,:] - y[b,j,:]||, stored diagonal-major:
// ddiag[b][(i+j)][j]  (padded 1023 x 512 per batch; holes never consumed).
// Writes are uncoalesced (stride 513 floats) but hidden by massive TLP;
// this buys fully coalesced reads in the serial wavefront kernel.
__global__ __launch_bounds__(256) void dist_diag_kernel(
    const float* __restrict__ x, const float* __restrict__ y,
    float* __restrict__ ddiag)
{
    const int b = blockIdx.z;
    const int i0 = blockIdx.y * 16;
    const int j0 = blockIdx.x * 16;
    __shared__ float xs[16 * 68];  // +4 float pad per row: bank-spread
    __shared__ float ys[16 * 68];
    const int t = threadIdx.x;     // 0..255
    const int lr = t >> 4;         // row to load
    const int lc = t & 15;         // float4 slot within row
    const float4* xsrc = (const float4*)(x + (((size_t)b * N_) + i0 + lr) * D_);
    const float4* ysrc = (const float4*)(y + (((size_t)b * N_) + j0 + lr) * D_);
    *(float4*)(&xs[lr * 68 + lc * 4]) = xsrc[lc];
    *(float4*)(&ys[lr * 68 + lc * 4]) = ysrc[lc];
    __syncthreads();

    const int ti = t >> 4, tj = t & 15;
    const float* xr = &xs[ti * 68];
    const float* yr = &ys[tj * 68];
    float acc = 0.f;
#pragma unroll
    for (int k = 0; k < 16; ++k) {
        float4 a = *(const float4*)(xr + 4 * k);
        float4 c = *(const float4*)(yr + 4 * k);
        float d0 = a.x - c.x, d1 = a.y - c.y, d2 = a.z - c.z, d3 = a.w - c.w;
        acc += d0 * d0 + d1 * d1 + d2 * d2 + d3 * d3;
    }
    const int i = i0 + ti, j = j0 + tj;
    ddiag[((size_t)b * NDIAG + (size_t)(i + j)) * N_ + j] = sqrtf(acc);
}

// Phase 2: wavefront soft-DTW. One block per batch, thread j owns column
// jj = j+1 of the (N+1)x(M+1) R matrix. Anti-diagonal s = i + jj.
// Triple-buffered LDS diagonals: A = diag s-1, Bf = diag s-2, C = diag s
// (write target). Read set {A,Bf} and write set {C} are disjoint ->
// ONE barrier per diagonal.
__global__ __launch_bounds__(512) void sdtw_kernel(
    const float* __restrict__ ddiag, float* __restrict__ out)
{
    const int b = blockIdx.x;
    const int j = threadIdx.x;  // 0..511, column jj = j+1
    const float* Db = ddiag + (size_t)b * NDIAG * N_;

    // Deterministic paths: path_i = path_j = arange(N) per batch.
    out[b * N_ + j] = (float)j;
    out[B_ * N_ + b * N_ + j] = (float)j;

    __shared__ float bufs[3][N_ + 1];
    float* A  = bufs[0];  // diag s-1
    float* Bf = bufs[1];  // diag s-2
    float* C  = bufs[2];  // diag s (write)
    A[j + 1]  = INFINITY;
    Bf[j + 1] = INFINITY;
    C[j + 1]  = INFINITY;
    if (j == 0) { A[0] = INFINITY; Bf[0] = 0.0f; C[0] = INFINITY; }
    __syncthreads();

    const float gamma = 0.1f, inv_g = 10.0f;
    float dcur = Db[j];      // diag index s-2 = 0 at s = 2
    float res = 0.f;
    for (int s = 2; s <= 2 * N_; ++s) {
        // Prefetch next diagonal's distance (coalesced); latency hides
        // under this iteration's softmin + barrier.
        float dnext = (s < 2 * N_) ? Db[(size_t)(s - 1) * N_ + j] : 0.0f;
        const int i = s - (j + 1);
        const bool active = (i >= 1) && (i <= N_);
        if (active) {
            float up   = A[j + 1];   // R[i-1][jj]
            float left = A[j];       // R[i][jj-1]
            float dg   = Bf[j];      // R[i-1][jj-1]
            float m = fminf(fminf(up, left), dg);
            float e = __expf((m - up) * inv_g) + __expf((m - left) * inv_g)
                    + __expf((m - dg) * inv_g);
            float r = dcur + m - gamma * __logf(e);
            C[j + 1] = r;
            res = r;
        }
        if (j == 0) C[0] = INFINITY;  // column-0 border of diag s
        __syncthreads();
        float* tmp = Bf; Bf = A; A = C; C = tmp;
        dcur = dnext;
    }
    // Thread 511's last active cell (s = 1024) is R[N][M].
    if (j == N_ - 1) out[2 * B_ * N_ + b] = res;
}

extern "C" void kernel_launch(void* const* d_in, const int* in_sizes, int n_in,
                              void* d_out, int out_size, void* d_ws, size_t ws_size,
                              hipStream_t stream) {
    const float* x = (const float*)d_in[0];
    const float* y = (const float*)d_in[1];
    float* out = (float*)d_out;
    float* ddiag = (float*)d_ws;  // needs 4*1023*512*4 B = 8.0 MB

    dim3 g1(N_ / 16, N_ / 16, B_);
    dist_diag_kernel<<<g1, 256, 0, stream>>>(x, y, ddiag);
    sdtw_kernel<<<B_, N_, 0, stream>>>(ddiag, out);
}

// Round 2
// 136.839 us; speedup vs baseline: 1.7220x; 1.7220x over previous
//
#include <hip/hip_runtime.h>
#include <math.h>

#define B_ 4
#define N_ 512
#define D_ 64
#define NDIAG (2 * N_ - 1)   // 1023 diagonal rows of D
#define WV 4                 // waves per block
#define K_ 16                // diagonals per chunk (between barriers)
#define DC0 9                // chunk stagger between adjacent waves (9*16=144 >= 128+16)
#define NCH 40               // chunks per wave: ceil(639/16)
#define CTOT (DC0 * (WV - 1) + NCH)  // 67
#define RING 1028            // non-wrapping ring: one slot per diagonal

// Phase 1: D[b][i][j] = ||x[b,i,:]-y[b,j,:]||, stored diagonal-major
// ddiag[b][(i+j)][j] so phase 2 reads coalesce along anti-diagonals.
__global__ __launch_bounds__(256) void dist_diag_kernel(
    const float* __restrict__ x, const float* __restrict__ y,
    float* __restrict__ ddiag)
{
    const int b = blockIdx.z;
    const int i0 = blockIdx.y * 16;
    const int j0 = blockIdx.x * 16;
    __shared__ float xs[16 * 68];
    __shared__ float ys[16 * 68];
    const int t = threadIdx.x;
    const int lr = t >> 4;
    const int lc = t & 15;
    const float4* xsrc = (const float4*)(x + (((size_t)b * N_) + i0 + lr) * D_);
    const float4* ysrc = (const float4*)(y + (((size_t)b * N_) + j0 + lr) * D_);
    *(float4*)(&xs[lr * 68 + lc * 4]) = xsrc[lc];
    *(float4*)(&ys[lr * 68 + lc * 4]) = ysrc[lc];
    __syncthreads();

    const int ti = t >> 4, tj = t & 15;
    const float* xr = &xs[ti * 68];
    const float* yr = &ys[tj * 68];
    float acc = 0.f;
#pragma unroll
    for (int k = 0; k < 16; ++k) {
        float4 a = *(const float4*)(xr + 4 * k);
        float4 c = *(const float4*)(yr + 4 * k);
        float d0 = a.x - c.x, d1 = a.y - c.y, d2 = a.z - c.z, d3 = a.w - c.w;
        acc += d0 * d0 + d1 * d1 + d2 * d2 + d3 * d3;
    }
    const int i = i0 + ti, j = j0 + tj;
    ddiag[((size_t)b * NDIAG + (size_t)(i + j)) * N_ + j] = sqrtf(acc);
}

// whole-wave shift: lane l receives lane l-1 (DPP wave_shr:1, VALU-latency)
__device__ __forceinline__ float dpp_shr1(float x) {
    int v = __builtin_amdgcn_update_dpp(0x7f800000 /*+inf as old*/, __float_as_int(x),
                                        0x138 /*WAVE_SHR1*/, 0xf, 0xf, false);
    return __int_as_float(v);
}

#if __has_builtin(__builtin_amdgcn_exp2f)
#define EXP2(x) __builtin_amdgcn_exp2f(x)
#else
#define EXP2(x) exp2f(x)
#endif
#if __has_builtin(__builtin_amdgcn_logf)
#define LOG2(x) __builtin_amdgcn_logf(x)
#else
#define LOG2(x) log2f(x)
#endif

// Phase 2: staggered register-resident soft-DTW.
// Wave w owns columns jj in [128w+1, 128w+128]; lane owns 2 adjacent columns.
// State per lane: rA?/rB? = its two columns' R values at diags s-1 / s-2.
// slot1 deps are in-lane; slot0 deps come from lane l-1 via DPP wave_shr:1,
// lane 0 reads the boundary column from an LDS ring written by wave w-1.
// Waves are staggered by DC0 chunks; one barrier per K_=16 diagonals.
__global__ __launch_bounds__(256) void sdtw_stag_kernel(
    const float* __restrict__ ddiag, float* __restrict__ out)
{
    const int b = blockIdx.x;
    const int tid = threadIdx.x;
    const int w = tid >> 6;
    const int lane = tid & 63;
    const float* Db = ddiag + (size_t)b * (NDIAG * (size_t)N_);

    // deterministic monotone paths: arange(512) for both
    for (int q = tid; q < N_; q += 256) {
        out[b * N_ + q] = (float)q;
        out[B_ * N_ + b * N_ + q] = (float)q;
    }

    // ring[w] = boundary column 128w (read by wave w, written by wave w-1).
    // ring[0] is the j=0 border: R[0][0]=0, R[i][0]=inf. ring[WV] = dump row.
    __shared__ __align__(16) float ring[WV + 1][RING];
    for (int q = tid; q < (WV + 1) * RING; q += 256)
        (&ring[0][0])[q] = (q == 0) ? 0.0f : INFINITY;
    __syncthreads();

    const float C1 = 14.4269504089f;    // (1/gamma)*log2(e)
    const float C2 = -0.069314718056f;  // -gamma*ln(2)
    const int jj0 = 128 * w + 2 * lane + 1;  // slot0 column (1-based)
    const int c0w = DC0 * w;
    const int s0w = 128 * w + 2;             // first diagonal for this wave
    const bool l0 = (lane == 0);
    const bool l63 = (lane == 63);
    const float* ringR = ring[w];
    float* ringW = ring[w + 1];

    // u0 = i0-1 where i0 = s - jj0 (row index of slot0); starts at -2*lane
    unsigned u0 = (unsigned)(-(2 * lane));
    float rA0 = INFINITY, rB0 = INFINITY, rA1 = INFINITY, rB1 = INFINITY;
    float lnL = INFINITY, ldL = INFINITY;

    const float* dcol = Db + (jj0 - 1);
    float2 dv[K_];
    // prime first chunk's distances (kernel-1 output is stream-ordered ready)
    {
#pragma unroll
        for (int t = 0; t < K_; ++t) {
            int row = s0w - 2 + t; if (row > NDIAG - 1) row = NDIAG - 1;
            dv[t] = *(const float2*)(dcol + (size_t)row * N_);
        }
    }

    for (int c = 0; c < CTOT; ++c) {
        const int lc = c - c0w;
        if (lc >= 0 && lc < NCH) {
            const int s0c = s0w + lc * K_;
            // bulk ring read: slots s0c-2 .. s0c+15 (16B-aligned, ds_read_b128)
            float rr[18];
            {
                const float4 q0 = *(const float4*)&ringR[s0c - 2];
                const float4 q1 = *(const float4*)&ringR[s0c + 2];
                const float4 q2 = *(const float4*)&ringR[s0c + 6];
                const float4 q3 = *(const float4*)&ringR[s0c + 10];
                const float2 q4 = *(const float2*)&ringR[s0c + 14];
                rr[0] = q0.x; rr[1] = q0.y; rr[2] = q0.z; rr[3] = q0.w;
                rr[4] = q1.x; rr[5] = q1.y; rr[6] = q1.z; rr[7] = q1.w;
                rr[8] = q2.x; rr[9] = q2.y; rr[10] = q2.z; rr[11] = q2.w;
                rr[12] = q3.x; rr[13] = q3.y; rr[14] = q3.z; rr[15] = q3.w;
                rr[16] = q4.x; rr[17] = q4.y;
            }
            if (lc == 0) {  // prime left/diag for the very first step
                lnL = l0 ? rr[1] : dpp_shr1(rA1);
                ldL = l0 ? rr[0] : dpp_shr1(rB1);
            }
#pragma unroll
            for (int t = 0; t < K_; ++t) {
                const float d0 = dv[t].x, d1 = dv[t].y;
                // slot0: up=rA0, left=lnL, diag=ldL
                float m0 = fminf(fminf(rA0, lnL), ldL);
                float mc0 = m0 * C1;
                float e00 = EXP2(fmaf(-rA0, C1, mc0));
                float e01 = EXP2(fmaf(-lnL, C1, mc0));
                float e02 = EXP2(fmaf(-ldL, C1, mc0));
                float r0 = fmaf(C2, LOG2(e00 + e01 + e02), m0) + d0;
                // slot1: up=rA1, left=rA0(old), diag=rB0(old)
                float m1 = fminf(fminf(rA1, rA0), rB0);
                float mc1 = m1 * C1;
                float e10 = EXP2(fmaf(-rA1, C1, mc1));
                float e11 = EXP2(fmaf(-rA0, C1, mc1));
                float e12 = EXP2(fmaf(-rB0, C1, mc1));
                float r1 = fmaf(C2, LOG2(e10 + e11 + e12), m1) + d1;
                const bool a0 = (u0 < 512u);         // i0 in [1,512]
                const bool a1 = ((u0 - 1u) < 512u);  // i1 in [1,512]
                const float oA0 = rA0, oA1 = rA1;
                rA0 = a0 ? r0 : oA0;  rB0 = oA0;     // keep-old: preserves inf
                rA1 = a1 ? r1 : oA1;  rB1 = oA1;     // borders & final value
                u0 += 1u;
                // rotate left/diag for next diagonal
                ldL = lnL;
                const float sh = dpp_shr1(rA1);
                lnL = l0 ? rr[t + 2] : sh;
                if (l63) ringW[s0c + t] = rA1;       // boundary column out
            }
        }
        // prefetch NEXT chunk's distances before the barrier (stay in flight)
        {
            const int lcn = c + 1 - c0w;
            if (lcn > 0 && lcn < NCH) {
                const int s0n = s0w + lcn * K_;
#pragma unroll
                for (int t = 0; t < K_; ++t) {
                    int row = s0n - 2 + t; if (row > NDIAG - 1) row = NDIAG - 1;
                    dv[t] = *(const float2*)(dcol + (size_t)row * N_);
                }
            }
        }
        // LDS-only drain + barrier (do NOT force vmcnt(0) like __syncthreads)
        asm volatile("s_waitcnt lgkmcnt(0)" ::: "memory");
        __builtin_amdgcn_s_barrier();
    }

    // R[512][512] lives in wave 3 / lane 63 / slot1 (kept by keep-old commit)
    if (w == WV - 1 && l63) out[2 * B_ * N_ + b] = rA1;
}

extern "C" void kernel_launch(void* const* d_in, const int* in_sizes, int n_in,
                              void* d_out, int out_size, void* d_ws, size_t ws_size,
                              hipStream_t stream) {
    const float* x = (const float*)d_in[0];
    const float* y = (const float*)d_in[1];
    float* out = (float*)d_out;
    float* ddiag = (float*)d_ws;  // 4*1023*512*4 B = 8.0 MB

    dim3 g1(N_ / 16, N_ / 16, B_);
    dist_diag_kernel<<<g1, 256, 0, stream>>>(x, y, ddiag);
    sdtw_stag_kernel<<<B_, 256, 0, stream>>>(ddiag, out);
}